// Round 11
// baseline (62.842 us; speedup 1.0000x reference)
//
#include <hip/hip_runtime.h>
#include <math.h>

#define CC 3
#define HH 720
#define WW 1280
#define HW (HH * WW)

// sorted-gather tiling: 64 wide x 4 tall per block, 256 threads
#define TW 64
#define TH 4
#define GX (WW / TW)    // 20
#define GY (HH / TH)    // 180
#define NWG (GX * GY)   // 3600 (div by 8 -> clean XCD swizzle)
#define NTHR 256

// fp16 workspace: copy A at even base, copy B at odd base (+1): any 8-tap
// window is ONE 4B-aligned global dwordx4. (proven round 3)
#define SW 1288
#define PLANE (HH * SW)
#define WS_HALFS (6 * PLANE + 8)
#define WS_BYTES ((size_t)WS_HALFS * 2)

#define RMAX 16                      // |floor(flow)| <= RMAX handled fast
#define NBY (TH - 1 + 2 * RMAX + 1)  // 36 distinct base-row values
#define NKEY (NBY * 2 + 1)           // 73 (row,parity) buckets + slow bucket

typedef float f4 __attribute__((ext_vector_type(4), aligned(4)));
typedef float f4a __attribute__((ext_vector_type(4), aligned(16)));
typedef _Float16 h8 __attribute__((ext_vector_type(8), aligned(4)));
typedef _Float16 h8a __attribute__((ext_vector_type(8), aligned(16)));
typedef _Float16 h2v __attribute__((ext_vector_type(2)));

#if __has_builtin(__builtin_amdgcn_fdot2)
#define HAVE_FDOT2 1
#endif

union CW { h2v h[4]; uint4 u; };

// cos(pi*k/8), sin(pi*k/8), (-1)^k for k = -3..4 (index j = k+3)
__constant__ float COSK[8] = {0.38268343f, 0.70710678f, 0.92387953f, 1.0f,
                              0.92387953f, 0.70710678f, 0.38268343f, 0.0f};
__constant__ float SINK[8] = {-0.92387953f, -0.70710678f, -0.38268343f, 0.0f,
                              0.38268343f, 0.70710678f, 0.92387953f, 1.0f};
__constant__ float SGNK[8] = {-1.0f, 1.0f, -1.0f, 1.0f, -1.0f, 1.0f, -1.0f, 1.0f};

__device__ __forceinline__ void sinc_weights(float s, float* wgt) {
    const float PI = 3.14159265358979f;
    float sp = __sinf(PI * s);
    float s8, c8;
    __sincosf(PI * s * 0.125f, &s8, &c8);
#pragma unroll
    for (int j = 0; j < 8; ++j) {
        float t = s - (float)(j - 3);
        float win = c8 * COSK[j] + s8 * SINK[j];
        float r = (t == 0.0f) ? 1.0f : __fdividef(sp * SGNK[j], PI * t);
        wgt[j] = win * r;
    }
}

// x-direction weights packed straight into 4x h2v
__device__ __forceinline__ void sinc_weights_h2(float s, h2v* cwp) {
    const float PI = 3.14159265358979f;
    float sp = __sinf(PI * s);
    float s8, c8;
    __sincosf(PI * s * 0.125f, &s8, &c8);
#pragma unroll
    for (int jj = 0; jj < 4; ++jj) {
        float w0, w1;
        {
            int j = 2 * jj;
            float t = s - (float)(j - 3);
            float win = c8 * COSK[j] + s8 * SINK[j];
            float r = (t == 0.0f) ? 1.0f : __fdividef(sp * SGNK[j], PI * t);
            w0 = win * r;
        }
        {
            int j = 2 * jj + 1;
            float t = s - (float)(j - 3);
            float win = c8 * COSK[j] + s8 * SINK[j];
            float r = (t == 0.0f) ? 1.0f : __fdividef(sp * SGNK[j], PI * t);
            w1 = win * r;
        }
        cwp[jj] = (h2v){(_Float16)w0, (_Float16)w1};
    }
}

__device__ __forceinline__ float dot8f(h8 v, const h2v* cw) {
#ifdef HAVE_FDOT2
    h2v* p = (h2v*)&v;
    float a = __builtin_amdgcn_fdot2(p[0], cw[0], 0.0f, false);
    a = __builtin_amdgcn_fdot2(p[1], cw[1], a, false);
    a = __builtin_amdgcn_fdot2(p[2], cw[2], a, false);
    a = __builtin_amdgcn_fdot2(p[3], cw[3], a, false);
    return a;
#else
    float r = 0.f;
#pragma unroll
    for (int j = 0; j < 8; ++j)
        r = fmaf((float)v[j], (float)cw[j >> 1][j & 1], r);
    return r;
#endif
}

// x (f32 CHW) -> two fp16 copies in ws (16B stores, 8 cols/thread)
__global__ __launch_bounds__(256) void conv_kernel(const float* __restrict__ x,
                                                   _Float16* __restrict__ ws) {
    int tid = blockIdx.x * blockDim.x + threadIdx.x;
    if (tid >= CC * HH * (WW / 8)) return;
    int k8 = tid % (WW / 8);
    int rest = tid / (WW / 8);       // c*HH + h
    int k = k8 * 8;
    const float* src = x + rest * WW + k;
    f4 va = *(const f4*)src;
    f4 vb = *(const f4*)(src + 4);
    float xm1 = (k8 == 0) ? src[0] : src[-1];
    _Float16 m1 = (_Float16)xm1;
    _Float16 v0 = (_Float16)va.x, v1 = (_Float16)va.y,
             v2 = (_Float16)va.z, v3 = (_Float16)va.w;
    _Float16 v4 = (_Float16)vb.x, v5 = (_Float16)vb.y,
             v6 = (_Float16)vb.z, v7 = (_Float16)vb.w;
    int dstA = rest * SW + k;
    *(h8a*)(ws + dstA) = (h8a){v0, v1, v2, v3, v4, v5, v6, v7};
    int dstB = 3 * PLANE + rest * SW + k;   // slot = element+1
    *(h8a*)(ws + dstB) = (h8a){m1, v0, v1, v2, v3, v4, v5, v6};
}

// exact f32 global path (border / large-flow pixels) — full clamping
__device__ __forceinline__ void pixel_slow(const float* __restrict__ x,
                                           int bx, int by,
                                           const float* cxw, const float* cyw,
                                           float& r0, float& r1, float& r2) {
    int xcl[8];
#pragma unroll
    for (int j = 0; j < 8; ++j) xcl[j] = min(max(bx + (j - 3), 0), WW - 1);
    r0 = 0.f; r1 = 0.f; r2 = 0.f;
#pragma unroll
    for (int i = 0; i < 8; ++i) {
        int o = min(max(by + (i - 3), 0), HH - 1) * WW;
        float cyi = cyw[i];
        const float* p0 = x + o;
        const float* p1 = p0 + HW;
        const float* p2 = p1 + HW;
        float rs0 = 0.f, rs1 = 0.f, rs2 = 0.f;
#pragma unroll
        for (int j = 0; j < 8; ++j) {
            float cj = cxw[j];
            rs0 = fmaf(p0[xcl[j]], cj, rs0);
            rs1 = fmaf(p1[xcl[j]], cj, rs1);
            rs2 = fmaf(p2[xcl[j]], cj, rs2);
        }
        r0 = fmaf(cyi, rs0, r0);
        r1 = fmaf(cyi, rs1, r1);
        r2 = fmaf(cyi, rs2, r2);
    }
}

__global__ __launch_bounds__(NTHR) void warp_kernel(const float* __restrict__ x,
                                                    const float* __restrict__ flow,
                                                    const _Float16* __restrict__ hx,
                                                    float* __restrict__ out) {
    __shared__ float sfx[NTHR], sfy[NTHR];          // flow; reused as res0/res1
    __shared__ unsigned short sid[NTHR];
    __shared__ int HIST[128], CUR[128];
    __shared__ uint4 scw[NTHR];                     // packed fp16 cx weights
    __shared__ __align__(16) float scy[NTHR * 8];   // f32 cy weights
    __shared__ int smeta[NTHR];                     // (s<<16)|(by&0xFFFF)
    __shared__ float res2s[NTHR];
    __shared__ int SF;                              // fast-pixel count

    int tid = threadIdx.x;

    int bid = blockIdx.x;
    int swz = (bid & 7) * (NWG / 8) + (bid >> 3);   // NWG%8==0: bijective
    int tx = swz % GX;
    int ty = swz / GX;
    int w0 = tx * TW;
    int h0 = ty * TH;

    if (tid < 128) HIST[tid] = 0;

    // phase 1: load flow (coalesced)
    int w = w0 + (tid & 63);
    int h = h0 + (tid >> 6);
    int idx = h * WW + w;
    float fx = flow[idx];
    float fy = flow[HW + idx];
    sfx[tid] = fx;
    sfy[tid] = fy;
    __syncthreads();

    // key = (base row, parity) bucket; slow pixels -> tail bucket
    int key;
    {
        int ix = (int)floorf(fx), iy = (int)floorf(fy);
        int s = w + ix - 3;
        int by = h + iy;
        bool fast = (iy >= -RMAX) && (iy <= RMAX) && (s >= 0) && (s <= WW - 8);
        key = fast ? ((by - (h0 - RMAX)) * 2 + (s & 1)) : (NKEY - 1);
    }
    atomicAdd(&HIST[key], 1);
    __syncthreads();

    // phase 2: single-wave shuffle scan (2 buckets/lane over 128)
    if (tid < 64) {
        int a = HIST[2 * tid], b = HIST[2 * tid + 1];
        int sum = a + b;
#pragma unroll
        for (int d = 1; d < 64; d <<= 1) {
            int vv = __shfl_up(sum, d, 64);
            if (tid >= d) sum += vv;
        }
        int excl = sum - a - b;
        CUR[2 * tid] = excl;
        CUR[2 * tid + 1] = excl + a;
        if (tid == (NKEY - 1) / 2) SF = excl;   // start of slow bucket = #fast
    }
    __syncthreads();

    // phase 3: scatter pixel ids into sorted order
    {
        int pos = atomicAdd(&CUR[key], 1);
        sid[pos] = (unsigned short)tid;
    }
    __syncthreads();

    // phase 4a: per sorted pixel — weights into LDS; slow pixels done here
    {
        int me = sid[tid];
        float mfx = sfx[me], mfy = sfy[me];
        int mw = w0 + (me & 63);
        int mh = h0 + (me >> 6);
        float rfx = floorf(mfx), rfy = floorf(mfy);
        float sx = mfx - rfx, sy = mfy - rfy;
        int ix = (int)rfx, iy = (int)rfy;
        int s = mw + ix - 3;
        int by = mh + iy;
        bool fast = (iy >= -RMAX) && (iy <= RMAX) && (s >= 0) && (s <= WW - 8);
        if (fast) {
            CW cwu;
            sinc_weights_h2(sx, cwu.h);
            scw[tid] = cwu.u;
            float cyw[8];
            sinc_weights(sy, cyw);
            f4a* pcy = (f4a*)&scy[tid * 8];
            pcy[0] = (f4a){cyw[0], cyw[1], cyw[2], cyw[3]};
            pcy[1] = (f4a){cyw[4], cyw[5], cyw[6], cyw[7]};
            smeta[tid] = (s << 16) | (by & 0xFFFF);
        } else {
            float cxw[8], cyw[8];
            sinc_weights(sx, cxw);
            sinc_weights(sy, cyw);
            float r0, r1, r2;
            pixel_slow(x, mw + ix, mh + iy, cxw, cyw, r0, r1, r2);
            sfx[me] = r0;      // res0 (this thread already consumed sfx[me])
            sfy[me] = r1;      // res1
            res2s[me] = r2;
        }
    }
    __syncthreads();

    // phase 4b: 8 lanes per fast pixel, lane i owns row i (dep depth = 3 loads)
    {
        int F = SF;
        int wv = tid >> 6;
        int ln = tid & 63;
        int grp = ln >> 3;
        int ri = ln & 7;
        for (int t = 0; t < 8; ++t) {
            int pi = wv * 64 + t * 8 + grp;
            if (pi < F) {
                int m = smeta[pi];
                int s2 = m >> 16;
                int by2 = (short)(m & 0xFFFF);
                int row = min(max(by2 + ri - 3, 0), HH - 1);
                const _Float16* hp =
                    hx + ((s2 & 1) ? (3 * PLANE + 1) : 0) + s2 + row * SW;
                h8 v0 = *(const h8*)(hp);
                h8 v1 = *(const h8*)(hp + PLANE);
                h8 v2 = *(const h8*)(hp + 2 * PLANE);
                CW cwu;
                cwu.u = scw[pi];
                float cyi = scy[pi * 8 + ri];
                float p0 = cyi * dot8f(v0, cwu.h);
                float p1 = cyi * dot8f(v1, cwu.h);
                float p2 = cyi * dot8f(v2, cwu.h);
#pragma unroll
                for (int d = 1; d < 8; d <<= 1) {
                    p0 += __shfl_xor(p0, d, 64);
                    p1 += __shfl_xor(p1, d, 64);
                    p2 += __shfl_xor(p2, d, 64);
                }
                if (ri == 0) {
                    int me2 = sid[pi];
                    sfx[me2] = p0;
                    sfy[me2] = p1;
                    res2s[me2] = p2;
                }
            }
        }
    }
    __syncthreads();

    // phase 5: coalesced stores (thread tid owns its original pixel)
    out[idx] = sfx[tid];
    out[HW + idx] = sfy[tid];
    out[2 * HW + idx] = res2s[tid];
}

// fallback (f32 gathers only) if workspace is too small
__global__ __launch_bounds__(256) void warp_kernel_f32(const float* __restrict__ x,
                                                       const float* __restrict__ flow,
                                                       float* __restrict__ out) {
    int idx = blockIdx.x * blockDim.x + threadIdx.x;
    if (idx >= HW) return;
    int w = idx % WW;
    int h = idx / WW;
    float fx = flow[idx], fy = flow[HW + idx];
    float rfx = floorf(fx), rfy = floorf(fy);
    int bx = w + (int)rfx, by = h + (int)rfy;
    float cxw[8], cyw[8];
    sinc_weights(fx - rfx, cxw);
    sinc_weights(fy - rfy, cyw);
    float r0, r1, r2;
    pixel_slow(x, bx, by, cxw, cyw, r0, r1, r2);
    out[idx] = r0;
    out[HW + idx] = r1;
    out[2 * HW + idx] = r2;
}

extern "C" void kernel_launch(void* const* d_in, const int* in_sizes, int n_in,
                              void* d_out, int out_size, void* d_ws, size_t ws_size,
                              hipStream_t stream) {
    const float* x = (const float*)d_in[0];
    const float* flow = (const float*)d_in[1];
    float* out = (float*)d_out;

    if (ws_size >= WS_BYTES) {
        _Float16* ws = (_Float16*)d_ws;
        int nconv = CC * HH * (WW / 8);
        conv_kernel<<<(nconv + 255) / 256, 256, 0, stream>>>(x, ws);
        warp_kernel<<<NWG, NTHR, 0, stream>>>(x, flow, ws, out);
    } else {
        warp_kernel_f32<<<(HW + 255) / 256, 256, 0, stream>>>(x, flow, out);
    }
}

// Round 12
// 47.440 us; speedup vs baseline: 1.3246x; 1.3246x over previous
//
#include <hip/hip_runtime.h>
#include <math.h>

#define CC 3
#define HH 720
#define WW 1280
#define HW (HH * WW)

// sorted-gather tiling: 64 wide x 4 tall per block, 256 threads, 1 px/thread
#define TW 64
#define TH 4
#define GX (WW / TW)    // 20
#define GY (HH / TH)    // 180
#define NWG (GX * GY)   // 3600 (div by 8 -> clean XCD swizzle)
#define NTHR 256

// fp16 workspace: copy A at even base, copy B at odd base (+1): any 8-tap
// window is ONE 4B-aligned global dwordx4. (proven round 3)
#define SW 1288
#define PLANE (HH * SW)
#define WS_HALFS (6 * PLANE + 8)
#define WS_BYTES ((size_t)WS_HALFS * 2)

#define RMAX 16                      // |floor(flow)| <= RMAX handled fast
#define NBY (TH - 1 + 2 * RMAX + 1)  // 36 distinct base-row values
#define NKEY (NBY * 2 + 1)           // 73 (row,parity) buckets + slow bucket

typedef float f4 __attribute__((ext_vector_type(4), aligned(4)));
typedef _Float16 h8 __attribute__((ext_vector_type(8), aligned(4)));
typedef _Float16 h2v __attribute__((ext_vector_type(2)));

#if __has_builtin(__builtin_amdgcn_fdot2)
#define HAVE_FDOT2 1
#endif

// cos(pi*k/8), sin(pi*k/8), (-1)^k for k = -3..4 (index j = k+3)
__constant__ float COSK[8] = {0.38268343f, 0.70710678f, 0.92387953f, 1.0f,
                              0.92387953f, 0.70710678f, 0.38268343f, 0.0f};
__constant__ float SINK[8] = {-0.92387953f, -0.70710678f, -0.38268343f, 0.0f,
                              0.38268343f, 0.70710678f, 0.92387953f, 1.0f};
__constant__ float SGNK[8] = {-1.0f, 1.0f, -1.0f, 1.0f, -1.0f, 1.0f, -1.0f, 1.0f};

__device__ __forceinline__ void sinc_weights(float s, float* wgt) {
    const float PI = 3.14159265358979f;
    float sp = __sinf(PI * s);
    float s8, c8;
    __sincosf(PI * s * 0.125f, &s8, &c8);
#pragma unroll
    for (int j = 0; j < 8; ++j) {
        float t = s - (float)(j - 3);
        float win = c8 * COSK[j] + s8 * SINK[j];
        float r = (t == 0.0f) ? 1.0f : __fdividef(sp * SGNK[j], PI * t);
        wgt[j] = win * r;
    }
}

__device__ __forceinline__ float dot8f(h8 v, const h2v* cw) {
#ifdef HAVE_FDOT2
    h2v* p = (h2v*)&v;
    float a = __builtin_amdgcn_fdot2(p[0], cw[0], 0.0f, false);
    a = __builtin_amdgcn_fdot2(p[1], cw[1], a, false);
    a = __builtin_amdgcn_fdot2(p[2], cw[2], a, false);
    a = __builtin_amdgcn_fdot2(p[3], cw[3], a, false);
    return a;
#else
    float r = 0.f;
#pragma unroll
    for (int j = 0; j < 8; ++j)
        r = fmaf((float)v[j], (float)cw[j >> 1][j & 1], r);
    return r;
#endif
}

// x (f32 CHW) -> two fp16 copies in ws (even-base and odd-base)
__global__ __launch_bounds__(256) void conv_kernel(const float* __restrict__ x,
                                                   _Float16* __restrict__ ws) {
    int tid = blockIdx.x * blockDim.x + threadIdx.x;
    if (tid >= CC * HH * (WW / 4)) return;
    int k4 = tid % (WW / 4);
    int rest = tid / (WW / 4);
    int k = k4 * 4;
    f4 v = *(const f4*)(x + rest * WW + k);
    int dst = rest * SW + k;
    _Float16 a = (_Float16)v.x, b = (_Float16)v.y,
             c = (_Float16)v.z, d = (_Float16)v.w;
    typedef _Float16 h4 __attribute__((ext_vector_type(4), aligned(8)));
    *(h4*)(ws + dst) = (h4){a, b, c, d};
    _Float16* wb = ws + 3 * PLANE + 1 + dst;
    wb[0] = a; wb[1] = b; wb[2] = c; wb[3] = d;
}

// exact f32 global path (border / large-flow pixels) — full clamping
__device__ __forceinline__ void pixel_slow(const float* __restrict__ x,
                                           int bx, int by,
                                           const float* cxw, const float* cyw,
                                           float& r0, float& r1, float& r2) {
    int xcl[8];
#pragma unroll
    for (int j = 0; j < 8; ++j) xcl[j] = min(max(bx + (j - 3), 0), WW - 1);
    r0 = 0.f; r1 = 0.f; r2 = 0.f;
#pragma unroll
    for (int i = 0; i < 8; ++i) {
        int o = min(max(by + (i - 3), 0), HH - 1) * WW;
        float cyi = cyw[i];
        const float* p0 = x + o;
        const float* p1 = p0 + HW;
        const float* p2 = p1 + HW;
        float rs0 = 0.f, rs1 = 0.f, rs2 = 0.f;
#pragma unroll
        for (int j = 0; j < 8; ++j) {
            float cj = cxw[j];
            rs0 = fmaf(p0[xcl[j]], cj, rs0);
            rs1 = fmaf(p1[xcl[j]], cj, rs1);
            rs2 = fmaf(p2[xcl[j]], cj, rs2);
        }
        r0 = fmaf(cyi, rs0, r0);
        r1 = fmaf(cyi, rs1, r1);
        r2 = fmaf(cyi, rs2, r2);
    }
}

__global__ __launch_bounds__(NTHR) void warp_kernel(const float* __restrict__ x,
                                                    const float* __restrict__ flow,
                                                    const _Float16* __restrict__ hx,
                                                    float* __restrict__ out) {
    __shared__ float sfx[NTHR], sfy[NTHR];
    __shared__ unsigned short sid[NTHR];
    __shared__ int HIST[128], CUR[128];

    int tid = threadIdx.x;

    int bid = blockIdx.x;
    int swz = (bid & 7) * (NWG / 8) + (bid >> 3);   // NWG%8==0: bijective
    int tx = swz % GX;
    int ty = swz / GX;
    int w0 = tx * TW;
    int h0 = ty * TH;

    if (tid < 128) HIST[tid] = 0;

    // phase 1: load flow (coalesced)
    int w = w0 + (tid & 63);
    int h = h0 + (tid >> 6);
    int idx = h * WW + w;
    float fx = flow[idx];
    float fy = flow[HW + idx];
    sfx[tid] = fx;
    sfy[tid] = fy;
    __syncthreads();

    // key = (base row, parity) bucket; slow pixels -> tail bucket
    int key;
    {
        int ix = (int)floorf(fx), iy = (int)floorf(fy);
        int s = w + ix - 3;
        int by = h + iy;
        bool fast = (iy >= -RMAX) && (iy <= RMAX) && (s >= 0) && (s <= WW - 8);
        key = fast ? ((by - (h0 - RMAX)) * 2 + (s & 1)) : (NKEY - 1);
    }
    atomicAdd(&HIST[key], 1);
    __syncthreads();

    // phase 2: single-wave shuffle scan (2 buckets/lane over 128)
    if (tid < 64) {
        int a = HIST[2 * tid], b = HIST[2 * tid + 1];
        int sum = a + b;
#pragma unroll
        for (int d = 1; d < 64; d <<= 1) {
            int vv = __shfl_up(sum, d, 64);
            if (tid >= d) sum += vv;
        }
        int excl = sum - a - b;
        CUR[2 * tid] = excl;
        CUR[2 * tid + 1] = excl + a;
    }
    __syncthreads();

    // phase 3: scatter pixel ids into sorted order
    {
        int pos = atomicAdd(&CUR[key], 1);
        sid[pos] = (unsigned short)tid;
    }
    __syncthreads();

    // phase 4: process sorted pixel (lanes share rows -> L1 locality)
    int me = sid[tid];
    float mfx = sfx[me], mfy = sfy[me];
    int mw = w0 + (me & 63);
    int mh = h0 + (me >> 6);
    float rfx = floorf(mfx), rfy = floorf(mfy);
    float sx = mfx - rfx, sy = mfy - rfy;
    int ix = (int)rfx, iy = (int)rfy;
    int s = mw + ix - 3;
    int by = mh + iy;
    bool fast = (iy >= -RMAX) && (iy <= RMAX) && (s >= 0) && (s <= WW - 8);

    float r0, r1, r2;
    if (fast) {
        int ro[8];
#pragma unroll
        for (int i = 0; i < 8; ++i)
            ro[i] = min(max(by + (i - 3), 0), HH - 1) * SW;
        const _Float16* hp = hx + ((s & 1) ? (3 * PLANE + 1) : 0) + s;

        float cxw[8], cyw[8];
        sinc_weights(sx, cxw);
        sinc_weights(sy, cyw);
        h2v cwp[4];
#pragma unroll
        for (int j = 0; j < 4; ++j)
            cwp[j] = (h2v){(_Float16)cxw[2 * j], (_Float16)cxw[2 * j + 1]};

        r0 = r1 = r2 = 0.f;
#pragma unroll
        for (int i = 0; i < 8; ++i) {
            h8 v0 = *(const h8*)(hp + ro[i]);
            h8 v1 = *(const h8*)(hp + ro[i] + PLANE);
            h8 v2 = *(const h8*)(hp + ro[i] + 2 * PLANE);
            float cyi = cyw[i];
            r0 = fmaf(cyi, dot8f(v0, cwp), r0);
            r1 = fmaf(cyi, dot8f(v1, cwp), r1);
            r2 = fmaf(cyi, dot8f(v2, cwp), r2);
        }
    } else {
        float cxw[8], cyw[8];
        sinc_weights(sx, cxw);
        sinc_weights(sy, cyw);
        pixel_slow(x, mw + ix, mh + iy, cxw, cyw, r0, r1, r2);
    }

    int oidx = mh * WW + mw;
    out[oidx] = r0;
    out[HW + oidx] = r1;
    out[2 * HW + oidx] = r2;
}

// fallback (f32 gathers only) if workspace is too small
__global__ __launch_bounds__(256) void warp_kernel_f32(const float* __restrict__ x,
                                                       const float* __restrict__ flow,
                                                       float* __restrict__ out) {
    int idx = blockIdx.x * blockDim.x + threadIdx.x;
    if (idx >= HW) return;
    int w = idx % WW;
    int h = idx / WW;
    float fx = flow[idx], fy = flow[HW + idx];
    float rfx = floorf(fx), rfy = floorf(fy);
    int bx = w + (int)rfx, by = h + (int)rfy;
    float cxw[8], cyw[8];
    sinc_weights(fx - rfx, cxw);
    sinc_weights(fy - rfy, cyw);
    float r0, r1, r2;
    pixel_slow(x, bx, by, cxw, cyw, r0, r1, r2);
    out[idx] = r0;
    out[HW + idx] = r1;
    out[2 * HW + idx] = r2;
}

extern "C" void kernel_launch(void* const* d_in, const int* in_sizes, int n_in,
                              void* d_out, int out_size, void* d_ws, size_t ws_size,
                              hipStream_t stream) {
    const float* x = (const float*)d_in[0];
    const float* flow = (const float*)d_in[1];
    float* out = (float*)d_out;

    if (ws_size >= WS_BYTES) {
        _Float16* ws = (_Float16*)d_ws;
        int nconv = CC * HH * (WW / 4);
        conv_kernel<<<(nconv + 255) / 256, 256, 0, stream>>>(x, ws);
        warp_kernel<<<NWG, NTHR, 0, stream>>>(x, flow, ws, out);
    } else {
        warp_kernel_f32<<<(HW + 255) / 256, 256, 0, stream>>>(x, flow, out);
    }
}